// Round 6
// baseline (269.333 us; speedup 1.0000x reference)
//
#include <hip/hip_runtime.h>
#include <stdint.h>

#define CIN  256
#define CR   32
#define COUT 560   // 32 + 528 pair channels

// One block per (b,h) row: 256 thr = 4 waves; lane = px (0..63), wave = cg
// (8 out-channels). Phase A: conv1x1+BN+ReLU for rows h-1..h+1 (halo
// recompute). Phase B: depthwise 3x3 + scale + dual L2 norms. Phase C:
// 560-plane store stream from registers.
__global__ __launch_bounds__(256, 4) void k_fused(
    const float* __restrict__ x,
    const float* __restrict__ wr,
    const float* __restrict__ gamma,
    const float* __restrict__ beta,
    const float* __restrict__ mean,
    const float* __restrict__ var,
    const float* __restrict__ dww,
    const float* __restrict__ scl,
    float* __restrict__ out)
{
    // phases A/B: zr[r][c][px] (r=0..2). phase C: znl[c][px] @0, twl[c][px] @2048
    __shared__ float buf[3 * CR * 64];           // 24 KB
    __shared__ float ps1[4 * 64], ps2[4 * 64];   // 2 KB
    __shared__ float dml[CR * 9];
    __shared__ float sc[CR];

    const int tid = threadIdx.x;
    for (int t = tid; t < CR * 9; t += 256) dml[t] = dww[t];   // 288 > 256: stride!
    if (tid < CR) sc[tid] = scl[tid];

    const int cg = __builtin_amdgcn_readfirstlane(tid >> 6);   // wave-uniform 0..3
    const int px = tid & 63;
    const int g  = blockIdx.x;          // 0..1023
    const int b  = g >> 6;
    const int h  = g & 63;
    const int ob = cg * 8;

    // ---------- Phase A: conv1x1 for rows h-1, h, h+1 ----------
    float acc[3][8];
    #pragma unroll
    for (int r = 0; r < 3; ++r)
        #pragma unroll
        for (int o = 0; o < 8; ++o) acc[r][o] = 0.f;

    const float* xb = x + (((size_t)b * CIN) << 12) + px;
    const int hc0 = (h == 0)  ? 0  : h - 1;    // clamped row (masked later)
    const int hc2 = (h == 63) ? 63 : h + 1;

    #pragma unroll 2
    for (int c0 = 0; c0 < CIN; c0 += 8) {
        float xv[8][3];
        #pragma unroll
        for (int k = 0; k < 8; ++k) {
            const float* xp = xb + ((size_t)(c0 + k) << 12);
            xv[k][0] = xp[hc0 << 6];
            xv[k][1] = xp[h   << 6];
            xv[k][2] = xp[hc2 << 6];
        }
        #pragma unroll
        for (int o = 0; o < 8; ++o) {
            const float* wp = wr + (ob + o) * CIN + c0;   // wave-uniform -> s_load
            #pragma unroll
            for (int k = 0; k < 8; ++k) {
                const float wv = wp[k];
                acc[0][o] = fmaf(xv[k][0], wv, acc[0][o]);
                acc[1][o] = fmaf(xv[k][1], wv, acc[1][o]);
                acc[2][o] = fmaf(xv[k][2], wv, acc[2][o]);
            }
        }
    }

    const bool v0 = (h > 0), v2 = (h < 63);
    float zrow[3][8];
    #pragma unroll
    for (int o = 0; o < 8; ++o) {
        const int oc = ob + o;
        const float inv = gamma[oc] / sqrtf(var[oc] + 1e-5f);
        const float bia = beta[oc] - mean[oc] * inv;
        zrow[0][o] = v0 ? fmaxf(fmaf(acc[0][o], inv, bia), 0.f) : 0.f;
        zrow[1][o] =      fmaxf(fmaf(acc[1][o], inv, bia), 0.f);
        zrow[2][o] = v2 ? fmaxf(fmaf(acc[2][o], inv, bia), 0.f) : 0.f;
    }
    #pragma unroll
    for (int r = 0; r < 3; ++r)
        #pragma unroll
        for (int o = 0; o < 8; ++o)
            buf[((r * CR) + ob + o) * 64 + px] = zrow[r][o];
    __syncthreads();   // zr visible (also covers dml/sc)

    // ---------- Phase B: 3x3 depthwise + scale, norm sums ----------
    float twv[8], zcv[8];
    float s1 = 0.f, s2 = 0.f;
    #pragma unroll
    for (int k = 0; k < 8; ++k) {
        const int c = ob + k;
        float a = 0.f;
        #pragma unroll
        for (int r = 0; r < 3; ++r) {
            const float* zp = &buf[(r * CR + c) * 64];
            const float vL = (px > 0)  ? zp[px - 1] : 0.f;
            const float vC =             zp[px];
            const float vR = (px < 63) ? zp[px + 1] : 0.f;
            a = fmaf(vL, dml[c * 9 + r * 3 + 0], a);
            a = fmaf(vC, dml[c * 9 + r * 3 + 1], a);
            a = fmaf(vR, dml[c * 9 + r * 3 + 2], a);
        }
        const float t = a * sc[c];
        twv[k] = t;
        zcv[k] = zrow[1][k];
        s1 = fmaf(zcv[k], zcv[k], s1);
        s2 = fmaf(t, t, s2);
    }
    ps1[cg * 64 + px] = s1;
    ps2[cg * 64 + px] = s2;
    __syncthreads();   // ps visible AND all taps on buf complete
    const float rn1 = 1.f / fmaxf(sqrtf(ps1[px] + ps1[64 + px] + ps1[128 + px] + ps1[192 + px]), 1e-6f);
    const float rn2 = 1.f / fmaxf(sqrtf(ps2[px] + ps2[64 + px] + ps2[128 + px] + ps2[192 + px]), 1e-6f);

    // reuse buf: znl @ [0..2047], twl @ [2048..4095] (safe: taps done)
    #pragma unroll
    for (int k = 0; k < 8; ++k) {
        buf[(ob + k) * 64 + px]        = zcv[k] * rn1;
        buf[2048 + (ob + k) * 64 + px] = twv[k] * rn2;
    }
    __syncthreads();

    // ---------- Phase C: reg-cache + dense store stream ----------
    float zn[CR], tw[CR];
    #pragma unroll
    for (int c = 0; c < CR; ++c) {
        zn[c] = buf[c * 64 + px];
        tw[c] = buf[2048 + c * 64 + px];
    }

    float* outb = out + (((size_t)b * COUT) << 12) + (h << 6) + px;
    #pragma unroll
    for (int P = 0; P < CR; ++P)
        if ((P & 3) == cg) outb[(size_t)P << 12] = zn[P];
    {
        int P = CR;
        #pragma unroll
        for (int i = 0; i < CR; ++i) {
            #pragma unroll
            for (int j = i; j < CR; ++j) {
                if ((P & 3) == cg) outb[(size_t)P << 12] = zn[i] * tw[j];
                ++P;
            }
        }
    }
}

extern "C" void kernel_launch(void* const* d_in, const int* in_sizes, int n_in,
                              void* d_out, int out_size, void* d_ws, size_t ws_size,
                              hipStream_t stream) {
    const float* x     = (const float*)d_in[0];
    const float* wr    = (const float*)d_in[1];
    const float* gamma = (const float*)d_in[2];
    const float* beta  = (const float*)d_in[3];
    const float* mean  = (const float*)d_in[4];
    const float* var   = (const float*)d_in[5];
    const float* dww   = (const float*)d_in[6];
    const float* scl   = (const float*)d_in[7];
    float* out = (float*)d_out;

    hipLaunchKernelGGL(k_fused, dim3(1024), dim3(256), 0, stream,
                       x, wr, gamma, beta, mean, var, dww, scl, out);
}